// Round 1
// baseline (231.813 us; speedup 1.0000x reference)
//
#include <hip/hip_runtime.h>

// Trilinear interpolation: grid (128,128,128,8) f32, 2M points.
// One thread per point; 8 corners x 32B (float4 x2) gathers; out 8 f32/point.

#define GS 128        // grid spatial size (all three dims)
#define GC 8          // channels (innermost)

__global__ __launch_bounds__(256) void trilerp_kernel(
    const float* __restrict__ coords,
    const float* __restrict__ grid,
    const float* __restrict__ bbox_min,
    const float* __restrict__ bbox_max,
    float* __restrict__ out,
    int n)
{
    int i = blockIdx.x * blockDim.x + threadIdx.x;
    if (i >= n) return;

    const float eps = 1e-6f;
    float b0x = bbox_min[0], b0y = bbox_min[1], b0z = bbox_min[2];
    float sx = fmaxf(bbox_max[0] - b0x, eps);
    float sy = fmaxf(bbox_max[1] - b0y, eps);
    float sz = fmaxf(bbox_max[2] - b0z, eps);

    float cx = coords[3 * i + 0];
    float cy = coords[3 * i + 1];
    float cz = coords[3 * i + 2];

    float nx = fminf(fmaxf((cx - b0x) / sx, 0.0f), 1.0f);
    float ny = fminf(fmaxf((cy - b0y) / sy, 0.0f), 1.0f);
    float nz = fminf(fmaxf((cz - b0z) / sz, 0.0f), 1.0f);

    float px = nx * (float)(GS - 1);
    float py = ny * (float)(GS - 1);
    float pz = nz * (float)(GS - 1);

    int x0 = (int)px;  // px >= 0, trunc == floor
    int y0 = (int)py;
    int z0 = (int)pz;
    // guard (px can be exactly 127.0 -> x0=127 ok; cannot exceed)
    int x1 = min(x0 + 1, GS - 1);
    int y1 = min(y0 + 1, GS - 1);
    int z1 = min(z0 + 1, GS - 1);

    float wx = fminf(fmaxf(px - (float)x0, 0.0f), 1.0f);
    float wy = fminf(fmaxf(py - (float)y0, 0.0f), 1.0f);
    float wz = fminf(fmaxf(pz - (float)z0, 0.0f), 1.0f);

    float ux = 1.0f - wx, uy = 1.0f - wy, uz = 1.0f - wz;

    // corner weights
    float w000 = ux * uy * uz;
    float w100 = wx * uy * uz;
    float w010 = ux * wy * uz;
    float w110 = wx * wy * uz;
    float w001 = ux * uy * wz;
    float w101 = wx * uy * wz;
    float w011 = ux * wy * wz;
    float w111 = wx * wy * wz;

    // grid addressed as float4: cell (x,y,z) -> 2 float4 at ((x*GS+y)*GS+z)*2
    const float4* g4 = (const float4*)grid;

    long long bx0 = (long long)x0 * GS;
    long long bx1 = (long long)x1 * GS;

    long long p000 = ((bx0 + y0) * GS + z0) * 2;
    long long p100 = ((bx1 + y0) * GS + z0) * 2;
    long long p010 = ((bx0 + y1) * GS + z0) * 2;
    long long p110 = ((bx1 + y1) * GS + z0) * 2;
    long long p001 = ((bx0 + y0) * GS + z1) * 2;
    long long p101 = ((bx1 + y0) * GS + z1) * 2;
    long long p011 = ((bx0 + y1) * GS + z1) * 2;
    long long p111 = ((bx1 + y1) * GS + z1) * 2;

    float4 a0 = g4[p000], a1 = g4[p000 + 1];
    float4 b0 = g4[p100], b1 = g4[p100 + 1];
    float4 c0 = g4[p010], c1 = g4[p010 + 1];
    float4 d0 = g4[p110], d1 = g4[p110 + 1];
    float4 e0 = g4[p001], e1 = g4[p001 + 1];
    float4 f0 = g4[p101], f1 = g4[p101 + 1];
    float4 h0 = g4[p011], h1 = g4[p011 + 1];
    float4 k0 = g4[p111], k1 = g4[p111 + 1];

    float4 o0, o1;
    o0.x = a0.x*w000 + b0.x*w100 + c0.x*w010 + d0.x*w110 + e0.x*w001 + f0.x*w101 + h0.x*w011 + k0.x*w111;
    o0.y = a0.y*w000 + b0.y*w100 + c0.y*w010 + d0.y*w110 + e0.y*w001 + f0.y*w101 + h0.y*w011 + k0.y*w111;
    o0.z = a0.z*w000 + b0.z*w100 + c0.z*w010 + d0.z*w110 + e0.z*w001 + f0.z*w101 + h0.z*w011 + k0.z*w111;
    o0.w = a0.w*w000 + b0.w*w100 + c0.w*w010 + d0.w*w110 + e0.w*w001 + f0.w*w101 + h0.w*w011 + k0.w*w111;
    o1.x = a1.x*w000 + b1.x*w100 + c1.x*w010 + d1.x*w110 + e1.x*w001 + f1.x*w101 + h1.x*w011 + k1.x*w111;
    o1.y = a1.y*w000 + b1.y*w100 + c1.y*w010 + d1.y*w110 + e1.y*w001 + f1.y*w101 + h1.y*w011 + k1.y*w111;
    o1.z = a1.z*w000 + b1.z*w100 + c1.z*w010 + d1.z*w110 + e1.z*w001 + f1.z*w101 + h1.z*w011 + k1.z*w111;
    o1.w = a1.w*w000 + b1.w*w100 + c1.w*w010 + d1.w*w110 + e1.w*w001 + f1.w*w101 + h1.w*w011 + k1.w*w111;

    float4* out4 = (float4*)out;
    out4[(long long)i * 2 + 0] = o0;
    out4[(long long)i * 2 + 1] = o1;
}

extern "C" void kernel_launch(void* const* d_in, const int* in_sizes, int n_in,
                              void* d_out, int out_size, void* d_ws, size_t ws_size,
                              hipStream_t stream) {
    const float* coords   = (const float*)d_in[0];
    const float* grid     = (const float*)d_in[1];
    const float* bbox_min = (const float*)d_in[2];
    const float* bbox_max = (const float*)d_in[3];
    float* out = (float*)d_out;

    int n = in_sizes[0] / 3;  // 2,000,000 points
    int block = 256;
    int nblocks = (n + block - 1) / block;
    trilerp_kernel<<<nblocks, block, 0, stream>>>(coords, grid, bbox_min, bbox_max, out, n);
}